// Round 5
// baseline (186.922 us; speedup 1.0000x reference)
//
#include <hip/hip_runtime.h>
#include <hip/hip_bf16.h>

#define BTC 16
#define NC 1024
#define DC 128
#define HC 8
#define HDC 16

typedef __attribute__((ext_vector_type(8)))  short bf16x8;   // 8 bf16 = 4 VGPR
typedef __attribute__((ext_vector_type(4)))  float f32x4;    // 16x16 C/D frag
typedef __attribute__((ext_vector_type(16))) float f32x16;   // 32x32 C/D frag
typedef __attribute__((ext_vector_type(4)))  short short4v;  // 8B pack

#if __has_builtin(__builtin_amdgcn_exp2f)
#define EXP2F(x) __builtin_amdgcn_exp2f(x)
#else
#define EXP2F(x) exp2f(x)
#endif

// q scale: 0.25 (1/sqrt(HD)) * log2(e) -> attention uses exp2 directly
#define QSCALE 0.36067376022224085f

union PK2 { short4v s4; __hip_bfloat162 h2[2]; };
union PK8 { bf16x8 v; short s[8]; __hip_bfloat162 h2[4]; };

static __device__ inline short f2bf(float f) {               // RNE f32->bf16
    unsigned u = __builtin_bit_cast(unsigned, f);
    u += 0x7fffu + ((u >> 16) & 1u);
    return (short)(u >> 16);
}

static __device__ inline bf16x8 pack8f(float4 a, float4 b) {
    PK8 f;
    f.h2[0] = __float22bfloat162_rn(make_float2(a.x, a.y));
    f.h2[1] = __float22bfloat162_rn(make_float2(a.z, a.w));
    f.h2[2] = __float22bfloat162_rn(make_float2(b.x, b.y));
    f.h2[3] = __float22bfloat162_rn(make_float2(b.z, b.w));
    return f.v;
}

// ---------------- qkv projection, fp32 in, bf16 out, LDS-free MFMA ----------
// block = 256 thr (4 waves), wave = 16 rows x 128 cols; grid (256, 3).
// y = 0: q (QSCALE folded), 1: k, 2: v stored transposed vt[bt][d][n].
__global__ __launch_bounds__(256)
void proj_qkv(const float* __restrict__ x,
              const float* __restrict__ Wq, const float* __restrict__ bq,
              const float* __restrict__ Wk, const float* __restrict__ bk,
              const float* __restrict__ Wv, const float* __restrict__ bv,
              short* __restrict__ qo, short* __restrict__ ko, short* __restrict__ vto)
{
    const int y = blockIdx.y;
    const float* W    = (y == 0) ? Wq : (y == 1) ? Wk : Wv;
    const float* bias = (y == 0) ? bq : (y == 1) ? bk : bv;
    const float scale = (y == 0) ? QSCALE : 1.0f;

    const int tid  = threadIdx.x;
    const int wave = tid >> 6;
    const int lane = tid & 63;
    const int l15  = lane & 15;
    const int quad = lane >> 4;
    const int rowA = blockIdx.x * 64 + wave * 16;

    f32x4 acc[8];
#pragma unroll
    for (int t = 0; t < 8; ++t) acc[t] = (f32x4){0.f, 0.f, 0.f, 0.f};

#pragma unroll
    for (int kk = 0; kk < DC; kk += 32) {
        const float* xp = &x[(size_t)(rowA + l15) * DC + kk + quad * 8];
        bf16x8 Af = pack8f(*(const float4*)xp, *(const float4*)(xp + 4));
#pragma unroll
        for (int t = 0; t < 8; ++t) {
            const float* wp = &W[(size_t)(t * 16 + l15) * DC + kk + quad * 8];
            bf16x8 Bf = pack8f(*(const float4*)wp, *(const float4*)(wp + 4));
            acc[t] = __builtin_amdgcn_mfma_f32_16x16x32_bf16(Af, Bf, acc[t], 0, 0, 0);
        }
    }

#pragma unroll
    for (int t = 0; t < 8; ++t) {
        int c = t * 16 + l15;
        float b = bias[c];
#pragma unroll
        for (int r = 0; r < 4; ++r) {
            int row = rowA + quad * 4 + r;
            float val = (acc[t][r] + b) * scale;
            if (y == 2)
                vto[(size_t)(row >> 10) * (DC * NC) + (size_t)c * NC + (row & (NC - 1))] = f2bf(val);
            else
                ((y == 0) ? qo : ko)[(size_t)row * DC + c] = f2bf(val);
        }
    }
}

// ---------------- fused attention + output projection -----------------------
// block = 512 thr = 8 waves = 8 heads; 32 q-rows; grid (32 qtiles, 16 bt).
// Superstep = 128 keys: adj staged to LDS (double buf), barrier, next-ss adj
// prefetched into regs; K/V frags batch-loaded. Per 32-key jj:
//   S^T = K·Q^T: ONE mfma_32x32x16 (d=16 exact). D[key(reg)][q=lane&31].
//   P = exp2(S)·adj -> bf16 -> wave-private LDS -> A-frag (16x16x32 layout)
//   ctx += P·V ; w += P·ones (identical D layout -> per-reg divide)
// Epilogue: ctx(32x128 bf16) -> LDS, block-local out = ctx@Wo^T + bo (fp32).
__global__ __launch_bounds__(512, 4)
void attn_fused(const short* __restrict__ qb, const short* __restrict__ kb,
                const short* __restrict__ vt, const float* __restrict__ adj,
                const float* __restrict__ Wo, const float* __restrict__ bo,
                float* __restrict__ out)
{
    __shared__ float As[2][32 * 132];   // adj superstep tiles, 33.8 KB
    __shared__ short Ps[8][32 * 40];    // wave-private P scratch, 20.5 KB
    __shared__ short Cs[32 * 136];      // ctx staging for out-proj, 8.7 KB

    const int tid  = threadIdx.x;
    const int wave = tid >> 6;           // = head h
    const int lane = tid & 63;
    const int l15  = lane & 15;
    const int quad = lane >> 4;
    const int l31  = lane & 31;
    const int lh   = lane >> 5;          // lane-high bit
    const int bt   = blockIdx.y;
    const int qt0  = blockIdx.x * 32;
    const int h    = wave;

    const size_t xb = (size_t)bt * NC * DC;
    const size_t ab = (size_t)bt * NC * NC;

    // Q B-frag for 32x32x16: B[n=q=l31][k=d=lh*8+j]  (QSCALE folded at proj)
    bf16x8 Bq = *(const bf16x8*)&qb[xb + (size_t)(qt0 + l31) * DC + h * HDC + lh * 8];

    PK8 ones;
#pragma unroll
    for (int j = 0; j < 8; ++j) ones.s[j] = (short)0x3F80;   // bf16 1.0

    f32x4 Cc[2], Cw[2];
#pragma unroll
    for (int s = 0; s < 2; ++s) {
        Cc[s] = (f32x4){0.f, 0.f, 0.f, 0.f};
        Cw[s] = (f32x4){0.f, 0.f, 0.f, 0.f};
    }

    // adj staging map: thread -> (row = tid>>4, cols (tid&15)*8 .. +7)
    const int arow = tid >> 4;
    const int acol = (tid & 15) * 8;
    const float* aptr = adj + ab + (size_t)(qt0 + arow) * NC + acol;
    float4 a0 = *(const float4*)aptr;
    float4 a1 = *(const float4*)(aptr + 4);

    short* Pw = &Ps[wave][0];
    const f32x16 z16 = {0.f,0.f,0.f,0.f,0.f,0.f,0.f,0.f,0.f,0.f,0.f,0.f,0.f,0.f,0.f,0.f};

    for (int ss = 0; ss < 8; ++ss) {
        const int p = ss & 1;
        *(float4*)&As[p][arow * 132 + acol]     = a0;
        *(float4*)&As[p][arow * 132 + acol + 4] = a1;
        __syncthreads();
        if (ss < 7) {                    // prefetch next superstep's adj (in flight a full ss)
            a0 = *(const float4*)(aptr + (ss + 1) * 128);
            a1 = *(const float4*)(aptr + (ss + 1) * 128 + 4);
        }

        const int jt0 = ss * 128;
        // batch-issue K/V frags for the 4 key tiles of this superstep
        bf16x8 Kf[4], Vf[4];
#pragma unroll
        for (int jj = 0; jj < 4; ++jj) {
            // K A-frag (32x32x16): A[m=key=l31][k=d=lh*8+j]
            Kf[jj] = *(const bf16x8*)&kb[xb + (size_t)(jt0 + jj * 32 + l31) * DC + h * HDC + lh * 8];
            // V B-frag (16x16x32): B[k=key=quad*8+j][n=d=l15] from transposed vt
            Vf[jj] = *(const bf16x8*)&vt[((size_t)bt * DC + h * HDC + l15) * NC + jt0 + jj * 32 + quad * 8];
        }

#pragma unroll
        for (int jj = 0; jj < 4; ++jj) {
            f32x16 S = __builtin_amdgcn_mfma_f32_32x32x16_bf16(Kf[jj], Bq, z16, 0, 0, 0);

            // P^T = exp2(S^T)*adj -> bf16 -> wave-private LDS [q][key]
#pragma unroll
            for (int rr = 0; rr < 4; ++rr) {
                int keyb = 8 * rr + 4 * lh;
                float4 a4 = *(const float4*)&As[p][l31 * 132 + jj * 32 + keyb];
                float p0 = EXP2F(S[4 * rr + 0]) * a4.x;
                float p1 = EXP2F(S[4 * rr + 1]) * a4.y;
                float p2 = EXP2F(S[4 * rr + 2]) * a4.z;
                float p3 = EXP2F(S[4 * rr + 3]) * a4.w;
                PK2 pk;
                pk.h2[0] = __float22bfloat162_rn(make_float2(p0, p1));
                pk.h2[1] = __float22bfloat162_rn(make_float2(p2, p3));
                *(short4v*)&Pw[l31 * 40 + keyb] = pk.s4;
            }
            __builtin_amdgcn_wave_barrier();

            // PV + row-sum: A[m=q(16)=l15][k=key=quad*8+j]
#pragma unroll
            for (int s = 0; s < 2; ++s) {
                bf16x8 Ap = *(const bf16x8*)&Pw[(s * 16 + l15) * 40 + quad * 8];
                Cc[s] = __builtin_amdgcn_mfma_f32_16x16x32_bf16(Ap, Vf[jj], Cc[s], 0, 0, 0);
                Cw[s] = __builtin_amdgcn_mfma_f32_16x16x32_bf16(Ap, ones.v, Cw[s], 0, 0, 0);
            }
            __builtin_amdgcn_wave_barrier();
        }
    }

    // ---- ctx -> LDS (bf16, stride 136 shorts: 272B = 17*16, b128-aligned) ----
#pragma unroll
    for (int s = 0; s < 2; ++s)
#pragma unroll
        for (int r = 0; r < 4; ++r) {
            float den = Cw[s][r];
            float rcp = den > 0.f ? 1.f / den : 0.f;
            int row = s * 16 + quad * 4 + r;
            Cs[row * 136 + h * HDC + l15] = f2bf(Cc[s][r] * rcp);
        }
    __syncthreads();

    // ---- fused out-projection: out(32x128) = ctx(32x128) @ Wo^T + bo --------
    // wave w: rows0 = (w&1)*16 ; col tiles t = (w>>1) and (w>>1)+4
    const int rows0 = (wave & 1) * 16;
    const int tbase = wave >> 1;
    f32x4 oacc[2];
    oacc[0] = (f32x4){0.f, 0.f, 0.f, 0.f};
    oacc[1] = (f32x4){0.f, 0.f, 0.f, 0.f};

#pragma unroll
    for (int kk = 0; kk < DC; kk += 32) {
        bf16x8 Ac = *(const bf16x8*)&Cs[(rows0 + l15) * 136 + kk + quad * 8];
#pragma unroll
        for (int ti = 0; ti < 2; ++ti) {
            int t = tbase + ti * 4;
            const float* wp = &Wo[(size_t)(t * 16 + l15) * DC + kk + quad * 8];
            bf16x8 Bf = pack8f(*(const float4*)wp, *(const float4*)(wp + 4));
            oacc[ti] = __builtin_amdgcn_mfma_f32_16x16x32_bf16(Ac, Bf, oacc[ti], 0, 0, 0);
        }
    }

#pragma unroll
    for (int ti = 0; ti < 2; ++ti) {
        int c = (tbase + ti * 4) * 16 + l15;
        float b = bo[c];
#pragma unroll
        for (int r = 0; r < 4; ++r) {
            int row = qt0 + rows0 + quad * 4 + r;
            out[((size_t)bt * NC + row) * DC + c] = oacc[ti][r] + b;
        }
    }
}

extern "C" void kernel_launch(void* const* d_in, const int* in_sizes, int n_in,
                              void* d_out, int out_size, void* d_ws, size_t ws_size,
                              hipStream_t stream)
{
    const float* x   = (const float*)d_in[0];
    const float* adj = (const float*)d_in[1];
    const float* Wq  = (const float*)d_in[2];
    const float* bq  = (const float*)d_in[3];
    const float* Wk  = (const float*)d_in[4];
    const float* bk  = (const float*)d_in[5];
    const float* Wv  = (const float*)d_in[6];
    const float* bv  = (const float*)d_in[7];
    const float* Wo  = (const float*)d_in[8];
    const float* bo  = (const float*)d_in[9];
    float* out = (float*)d_out;

    const size_t tok = (size_t)BTC * NC * DC;   // 2,097,152
    short* qbuf = (short*)d_ws;
    short* kbuf = qbuf + tok;
    short* vt   = kbuf + tok;

    dim3 pgrid(256, 3);
    proj_qkv<<<pgrid, 256, 0, stream>>>(x, Wq, bq, Wk, bk, Wv, bv, qbuf, kbuf, vt);

    dim3 agrid(NC / 32, BTC);
    attn_fused<<<agrid, 512, 0, stream>>>(qbuf, kbuf, vt, adj, Wo, bo, out);
}